// Round 16
// baseline (113.664 us; speedup 1.0000x reference)
//
#include <hip/hip_runtime.h>

#define N_INST 4096
#define D_FEAT 512
#define NHEAD 8
#define NPAIR 131072
#define SPLITK 8

typedef __attribute__((ext_vector_type(8))) short short8;
typedef __attribute__((ext_vector_type(4))) float f32x4;
typedef __attribute__((ext_vector_type(4))) unsigned short u16x4;
typedef __attribute__((ext_vector_type(8))) unsigned short u16x8;

__device__ inline unsigned short f2bf(float f) {
  union { float f; unsigned u; } v; v.f = f;
  unsigned r = v.u + 0x7fffu + ((v.u >> 16) & 1u);
  return (unsigned short)(r >> 16);
}
__device__ inline float bf2f(unsigned short b) {
  union { unsigned u; float f; } v; v.u = ((unsigned)b) << 16; return v.f;
}
__device__ inline void gload16(const void* g, void* l) {
  __builtin_amdgcn_global_load_lds((const __attribute__((address_space(1))) unsigned int*)g,
                                   (__attribute__((address_space(3))) unsigned int*)l, 16, 0, 0);
}

// ---------------- both weight casts in one launch (y=0 -> w_q, y=1 -> w_k) ----------------
__global__ __launch_bounds__(256) void k_castw(const float* __restrict__ wq,
                                               const float* __restrict__ wk,
                                               unsigned short* __restrict__ dst) {
  const float* src = blockIdx.y ? wk : wq;
  unsigned short* d = dst + (size_t)blockIdx.y * D_FEAT * D_FEAT;
  int i = (blockIdx.x * 256 + threadIdx.x) * 4;
  float4 v = *(const float4*)&src[i];
  ushort4 o;
  o.x = f2bf(v.x); o.y = f2bf(v.y); o.z = f2bf(v.z); o.w = f2bf(v.w);
  *(ushort4*)&d[i] = o;
}

// ---------------- x (4096x512 f32) -> xb bf16 AND xT bf16 (512x4096), one read ----------------
__global__ __launch_bounds__(256) void k_xprep(const float* __restrict__ x,
                                               unsigned short* __restrict__ xb,
                                               unsigned short* __restrict__ xT) {
  __shared__ float t[32][33];
  int bx = blockIdx.x, by = blockIdx.y;
  int tx = threadIdx.x & 31, ty = threadIdx.x >> 5;
  #pragma unroll
  for (int r = 0; r < 4; ++r) {
    int row = by * 32 + ty + r * 8;
    float v = x[(size_t)row * D_FEAT + bx * 32 + tx];
    t[ty + r * 8][tx] = v;
    xb[(size_t)row * D_FEAT + bx * 32 + tx] = f2bf(v);
  }
  __syncthreads();
  #pragma unroll
  for (int r = 0; r < 4; ++r)
    xT[(size_t)(bx * 32 + ty + r * 8) * N_INST + by * 32 + tx] = f2bf(t[tx][ty + r * 8]);
}

// ---------------- 2 rows/block: bf16 mask (diag=1) + off-diag count + nibble validity ----------------
__global__ __launch_bounds__(256) void k_mask_acnt(const float* __restrict__ agg,
                                                   unsigned short* __restrict__ maskb,
                                                   int* __restrict__ acnt,
                                                   unsigned char* __restrict__ vbits) {
  int i0 = blockIdx.x * 2;
  const f32x4* r0 = (const f32x4*)(agg + (size_t)i0 * N_INST);
  const f32x4* r1 = (const f32x4*)(agg + (size_t)(i0 + 1) * N_INST);
  u16x4* m0 = (u16x4*)(maskb + (size_t)i0 * N_INST);
  u16x4* m1 = (u16x4*)(maskb + (size_t)(i0 + 1) * N_INST);
  unsigned char* v0r = vbits + (size_t)i0 * (N_INST / 4);
  unsigned char* v1r = vbits + (size_t)(i0 + 1) * (N_INST / 4);
  int tid = threadIdx.x;
  f32x4 v[8];
  #pragma unroll
  for (int u = 0; u < 4; ++u) {
    v[u]     = __builtin_nontemporal_load(&r0[u * 256 + tid]);
    v[4 + u] = __builtin_nontemporal_load(&r1[u * 256 + tid]);
  }
  int cnt0 = 0, cnt1 = 0;
  #pragma unroll
  for (int u = 0; u < 4; ++u) {
    int t = u * 256 + tid;
    int j = t * 4;
    {
      f32x4 w = v[u];
      int b0 = (w[0] != 0.f), b1 = (w[1] != 0.f), b2 = (w[2] != 0.f), b3 = (w[3] != 0.f);
      u16x4 m;
      m[0] = b0 ? 0x3F80 : 0; m[1] = b1 ? 0x3F80 : 0;
      m[2] = b2 ? 0x3F80 : 0; m[3] = b3 ? 0x3F80 : 0;
      cnt0 += b0 + b1 + b2 + b3;
      v0r[t] = (unsigned char)(b0 | (b1 << 1) | (b2 << 2) | (b3 << 3));
      if (i0 >= j && i0 < j + 4) {
        int d = i0 - j;
        m[d] = 0x3F80;
        cnt0 -= (w[d] != 0.f);
      }
      __builtin_nontemporal_store(m, &m0[t]);
    }
    {
      f32x4 w = v[4 + u];
      int i1 = i0 + 1;
      int b0 = (w[0] != 0.f), b1 = (w[1] != 0.f), b2 = (w[2] != 0.f), b3 = (w[3] != 0.f);
      u16x4 m;
      m[0] = b0 ? 0x3F80 : 0; m[1] = b1 ? 0x3F80 : 0;
      m[2] = b2 ? 0x3F80 : 0; m[3] = b3 ? 0x3F80 : 0;
      cnt1 += b0 + b1 + b2 + b3;
      v1r[t] = (unsigned char)(b0 | (b1 << 1) | (b2 << 2) | (b3 << 3));
      if (i1 >= j && i1 < j + 4) {
        int d = i1 - j;
        m[d] = 0x3F80;
        cnt1 -= (w[d] != 0.f);
      }
      __builtin_nontemporal_store(m, &m1[t]);
    }
  }
  #pragma unroll
  for (int msk = 1; msk < 64; msk <<= 1) {
    cnt0 += __shfl_xor(cnt0, msk);
    cnt1 += __shfl_xor(cnt1, msk);
  }
  __shared__ int wsum[4][2];
  if ((threadIdx.x & 63) == 0) {
    wsum[threadIdx.x >> 6][0] = cnt0;
    wsum[threadIdx.x >> 6][1] = cnt1;
  }
  __syncthreads();
  if (threadIdx.x == 0)
    acnt[i0] = wsum[0][0] + wsum[1][0] + wsum[2][0] + wsum[3][0];
  if (threadIdx.x == 1)
    acnt[i0 + 1] = wsum[0][1] + wsum[1][1] + wsum[2][1] + wsum[3][1];
}

// ---------------- NT bf16 MFMA GEMM, BM=128, BN/NB templated, BK=64 ----------------
// NB=2: double-buffered LDS (64KB, 2 blocks/CU) — proven for the QK projection.
// NB=1: m97-style single-buffer (32KB LDS -> 4 blocks/CU with launch_bounds(256,4));
//       per guide m99/m100/m114: explicit dbuf adds nothing once multi-block TLP
//       covers the staging latency; occupancy is the lever.
template<int BIAS, int CBF16, int BN, int NB>
__global__ __launch_bounds__(256, NB == 1 ? 4 : 2) void k_gemm(
    const unsigned short* __restrict__ A,
    const unsigned short* __restrict__ B,
    const float* __restrict__ bias0,
    const float* __restrict__ bias1,
    void* __restrict__ Cv,
    int M, int N, int K, int klen) {
  constexpr int NI = BN / 32;
  constexpr int BCH = BN / 32;
  __shared__ __align__(16) unsigned short lA[NB][128 * 64];
  __shared__ __align__(16) unsigned short lB[NB][BN * 64];
  int tid = threadIdx.x, wave = tid >> 6, lane = tid & 63;
  int wm = wave & 1, wn = wave >> 1;
  int gx = gridDim.x;
  int nxy = gx * gridDim.y;
  int lin = blockIdx.x + gx * blockIdx.y;
  int nch = nxy >> 3;
  int nl = (lin & 7) * nch + (lin >> 3);
  int bx = nl % gx, by = nl / gx;
  int bm = by * 128, bn = bx * BN;
  int kbase = blockIdx.z * klen;
  int srow = lane >> 3;
  int sg = (lane & 7) ^ srow;
  const unsigned short* ag[4];
  const unsigned short* bg[BCH];
  #pragma unroll
  for (int p = 0; p < 4; ++p) {
    int row = (wave * 4 + p) * 8 + srow;
    ag[p] = A + (size_t)(bm + row) * K + kbase + sg * 8;
  }
  #pragma unroll
  for (int p = 0; p < BCH; ++p) {
    int row = (wave * BCH + p) * 8 + srow;
    bg[p] = B + (size_t)(bn + row) * K + kbase + sg * 8;
  }
  auto stage = [&](int buf) {
    #pragma unroll
    for (int p = 0; p < 4; ++p) { gload16(ag[p], &lA[buf][(wave * 4 + p) * 512]); ag[p] += 64; }
    #pragma unroll
    for (int p = 0; p < BCH; ++p) { gload16(bg[p], &lB[buf][(wave * BCH + p) * 512]); bg[p] += 64; }
  };
  f32x4 acc[4][NI] = {};
  int nt = klen / 64;
  if (NB == 2) { stage(0); __syncthreads(); }
  int cur = 0;
  int lrow = lane & 15, glq = lane >> 4;
  for (int t = 0; t < nt; ++t) {
    if (NB == 2) {
      if (t + 1 < nt) stage(cur ^ 1);
    } else {
      stage(0);
      __syncthreads();
    }
    short8 bf[2][NI];
    #pragma unroll
    for (int kk = 0; kk < 2; ++kk)
      #pragma unroll
      for (int ni = 0; ni < NI; ++ni) {
        int row = wn * (BN / 2) + ni * 16 + lrow;
        int pg = (kk * 4 + glq) ^ (row & 7);
        bf[kk][ni] = *(const short8*)&lB[cur][row * 64 + pg * 8];
      }
    #pragma unroll
    for (int mi = 0; mi < 4; ++mi)
      #pragma unroll
      for (int kk = 0; kk < 2; ++kk) {
        int row = wm * 64 + mi * 16 + lrow;
        int pg = (kk * 4 + glq) ^ (row & 7);
        short8 af = *(const short8*)&lA[cur][row * 64 + pg * 8];
        #pragma unroll
        for (int ni = 0; ni < NI; ++ni)
          acc[mi][ni] = __builtin_amdgcn_mfma_f32_16x16x32_bf16(af, bf[kk][ni], acc[mi][ni], 0, 0, 0);
      }
    __syncthreads();
    if (NB == 2) cur ^= 1;
  }
  #pragma unroll
  for (int mi = 0; mi < 4; ++mi)
    #pragma unroll
    for (int ni = 0; ni < NI; ++ni) {
      int col = bn + wn * (BN / 2) + ni * 16 + lrow;
      float bv = 0.f;
      if (BIAS) bv = (col < 512) ? bias0[col] : bias1[col - 512];
      #pragma unroll
      for (int j = 0; j < 4; ++j) {
        int row = bm + wm * 64 + mi * 16 + glq * 4 + j;
        float vv = acc[mi][ni][j] + bv;
        if (CBF16) {
          unsigned short* C = (unsigned short*)Cv + (size_t)blockIdx.z * M * N;
          C[(size_t)row * N + col] = f2bf(vv);
        } else {
          float* C = (float*)Cv + (size_t)blockIdx.z * M * N;
          C[(size_t)row * N + col] = vv;
        }
      }
    }
}

// ---------------- per-pair exp(score): 16 lanes/pair (4 pairs/wave) ----------------
// Continuing the MLP curve (R15: 2->4 outstanding was -4us): each lane now loads
// 4 Q-chunks + 4 K-chunks = 8 outstanding 16B gathers. Chunk c = heads 2c,2c+1;
// lanes 0-7 of the 16-lane group reduce head 2c, lanes 8-15 head 2c+1.
__global__ __launch_bounds__(256) void k_scores(const unsigned short* __restrict__ QKb,
                                                const int* __restrict__ pairs,
                                                const unsigned char* __restrict__ vbits,
                                                float* __restrict__ es,
                                                float* __restrict__ sumexp,
                                                int* __restrict__ scnt) {
  int wave = threadIdx.x >> 6, lane = threadIdx.x & 63;
  int q = lane >> 4, ql = lane & 15;
  int e = (blockIdx.x * 4 + wave) * 4 + q;
  int2 pr = *(const int2*)&pairs[2 * e];
  int sub = pr.x, obj = pr.y;
  unsigned char nb = vbits[(size_t)sub * (N_INST / 4) + (obj >> 2)];
  bool valid = (sub != obj) && ((nb >> (obj & 3)) & 1);
  if (!valid && ql == 0) es[(size_t)e * 8] = -1.f;
  if (__ballot(valid) == 0ull) return;   // all 4 pairs invalid -> retire wave
  float p[4] = {0.f, 0.f, 0.f, 0.f};
  if (valid) {
    short8 qv[4], kv[4];
    #pragma unroll
    for (int c = 0; c < 4; ++c) {
      qv[c] = *(const short8*)&QKb[(size_t)sub * 1024 + c * 128 + ql * 8];
      kv[c] = *(const short8*)&QKb[(size_t)obj * 1024 + 512 + c * 128 + ql * 8];
    }
    #pragma unroll
    for (int c = 0; c < 4; ++c)
      #pragma unroll
      for (int j = 0; j < 8; ++j)
        p[c] += bf2f((unsigned short)qv[c][j]) * bf2f((unsigned short)kv[c][j]);
  }
  #pragma unroll
  for (int c = 0; c < 4; ++c) {
    p[c] += __shfl_xor(p[c], 1);
    p[c] += __shfl_xor(p[c], 2);
    p[c] += __shfl_xor(p[c], 4);
  }
  if (valid && (ql & 7) == 0) {
    int hi = ql >> 3;                   // 0 or 1
    #pragma unroll
    for (int c = 0; c < 4; ++c) {
      int h = 2 * c + hi;
      float ev = expf(p[c] * 0.125f);   // / sqrt(64)
      es[(size_t)e * 8 + h] = ev;
      atomicAdd(&sumexp[sub * 8 + h], ev);
    }
    if (ql == 0) atomicAdd(&scnt[sub], 1);
  }
}

// ---------------- per-row denominators -> invden, base ----------------
__global__ __launch_bounds__(256) void k_denom(const float* __restrict__ sumexp,
                                               const int* __restrict__ scnt,
                                               const int* __restrict__ acnt,
                                               float* __restrict__ invden,
                                               float* __restrict__ base) {
  int i = blockIdx.x * 256 + threadIdx.x;
  if (i >= N_INST) return;
  float c0 = (float)(acnt[i] - scnt[i]);
  const float E0 = expf(1e-7f);
  float bsum = 0.f;
  #pragma unroll
  for (int h = 0; h < NHEAD; ++h) {
    float inv = 1.0f / (E0 + c0 + sumexp[i * NHEAD + h]);
    invden[i * NHEAD + h] = inv;
    bsum += inv;
  }
  base[i] = bsum * (1.0f / NHEAD);
}

// ---------------- scatter ratio entries into mask ----------------
__global__ __launch_bounds__(256) void k_scatter(const int* __restrict__ pairs,
                                                 const float* __restrict__ es,
                                                 const float* __restrict__ invden,
                                                 const float* __restrict__ base,
                                                 unsigned short* __restrict__ maskb) {
  int e = blockIdx.x * 256 + threadIdx.x;
  if (e >= NPAIR) return;
  float4 e0 = *(const float4*)&es[(size_t)e * 8];
  if (e0.x < 0.f) return;
  float4 e1 = *(const float4*)&es[(size_t)e * 8 + 4];
  int sub = pairs[2 * e], obj = pairs[2 * e + 1];
  const float* inv = &invden[sub * 8];
  float f = e0.x * inv[0] + e0.y * inv[1] + e0.z * inv[2] + e0.w * inv[3] +
            e1.x * inv[4] + e1.y * inv[5] + e1.z * inv[6] + e1.w * inv[7];
  maskb[(size_t)sub * N_INST + obj] = f2bf(f * 0.125f / base[sub]);
}

// ---------------- reduce split-K=8 bf16 partials + row scale ----------------
__global__ __launch_bounds__(256) void k_redscale(const unsigned short* __restrict__ P,
                                                  const float* __restrict__ base,
                                                  float* __restrict__ out) {
  size_t idx = ((size_t)blockIdx.x * 256 + threadIdx.x) * 8;
  int i = (int)(idx >> 9);
  const size_t S = (size_t)N_INST * 512;
  u16x8 v[SPLITK];
  #pragma unroll
  for (int z = 0; z < SPLITK; ++z)
    v[z] = *(const u16x8*)&P[idx + z * S];
  float s = base[i];
  float4 o0, o1;
  #pragma unroll
  for (int j = 0; j < 4; ++j) {
    float a = 0.f, b = 0.f;
    #pragma unroll
    for (int z = 0; z < SPLITK; ++z) {
      a += bf2f(v[z][j]);
      b += bf2f(v[z][4 + j]);
    }
    ((float*)&o0)[j] = s * a;
    ((float*)&o1)[j] = s * b;
  }
  *(float4*)&out[idx] = o0;
  *(float4*)&out[idx + 4] = o1;
}

extern "C" void kernel_launch(void* const* d_in, const int* in_sizes, int n_in,
                              void* d_out, int out_size, void* d_ws, size_t ws_size,
                              hipStream_t stream) {
  const float* x   = (const float*)d_in[0];
  const float* agg = (const float*)d_in[1];
  const int*   prs = (const int*)d_in[2];
  const float* w_q = (const float*)d_in[3];
  const float* b_q = (const float*)d_in[4];
  const float* w_k = (const float*)d_in[5];
  const float* b_k = (const float*)d_in[6];
  float* out = (float*)d_out;

  char* ws = (char*)d_ws;
  size_t off = 0;
  auto alloc = [&](size_t bytes) -> void* {
    void* p = ws + off;
    off += (bytes + 255) & ~(size_t)255;
    return p;
  };
  unsigned short* xb    = (unsigned short*)alloc((size_t)N_INST * D_FEAT * 2);
  unsigned short* xbT   = (unsigned short*)alloc((size_t)D_FEAT * N_INST * 2);
  unsigned short* wqkb  = (unsigned short*)alloc((size_t)1024 * D_FEAT * 2);
  void*           QKP   = alloc((size_t)N_INST * 512 * 2 * SPLITK);  // 8MB QK table; reused as 8x bf16 partials (32MB)
  float*          es    = (float*)alloc((size_t)NPAIR * NHEAD * 4);
  float*          sumexp= (float*)alloc((size_t)N_INST * NHEAD * 4);
  int*            scnt  = (int*)alloc((size_t)N_INST * 4);
  int*            acnt  = (int*)alloc((size_t)N_INST * 4);
  float*          invden= (float*)alloc((size_t)N_INST * NHEAD * 4);
  float*          base  = (float*)alloc((size_t)N_INST * 4);
  unsigned char*  vbits = (unsigned char*)alloc((size_t)N_INST * (N_INST / 4));
  unsigned short* maskb = (unsigned short*)alloc((size_t)N_INST * N_INST * 2);

  // sumexp (128KB, 256-aligned) and scnt (16KB) are adjacent -> one memset
  hipMemsetAsync(sumexp, 0, (size_t)N_INST * NHEAD * 4 + (size_t)N_INST * 4, stream);

  k_castw<<<dim3(D_FEAT * D_FEAT / 4 / 256, 2), 256, 0, stream>>>(w_q, w_k, wqkb);
  k_xprep<<<dim3(D_FEAT / 32, N_INST / 32), 256, 0, stream>>>(x, xb, xbT);
  k_mask_acnt<<<dim3(N_INST / 2), 256, 0, stream>>>(agg, maskb, acnt, vbits);

  // fused Q|K projection (dbuf, 2 blocks/CU): C (4096x1024 bf16) = xb * wqkb^T + bias
  k_gemm<1, 1, 64, 2><<<dim3(1024 / 64, N_INST / 128, 1), 256, 0, stream>>>(
      xb, wqkb, b_q, b_k, QKP, N_INST, 1024, D_FEAT, D_FEAT);

  k_scores<<<dim3(NPAIR / 16), 256, 0, stream>>>((const unsigned short*)QKP, prs, vbits, es, sumexp, scnt);
  k_denom<<<dim3(N_INST / 256), 256, 0, stream>>>(sumexp, scnt, acnt, invden, base);
  k_scatter<<<dim3(NPAIR / 256), 256, 0, stream>>>(prs, es, invden, base, maskb);

  // bf16 partials = maskb (4096x4096) * xbT (512x4096)^T, 128x128 tile,
  // single-buffer LDS (m97 structure), 4 blocks/CU, split-K=8
  k_gemm<0, 1, 128, 1><<<dim3(512 / 128, N_INST / 128, SPLITK), 256, 0, stream>>>(
      maskb, xbT, nullptr, nullptr, QKP, N_INST, 512, N_INST, N_INST / SPLITK);

  k_redscale<<<dim3(N_INST * 512 / 8 / 256), 256, 0, stream>>>((const unsigned short*)QKP, base, out);
}

// Round 17
// 108.928 us; speedup vs baseline: 1.0435x; 1.0435x over previous
//
#include <hip/hip_runtime.h>

#define N_INST 4096
#define D_FEAT 512
#define NHEAD 8
#define NPAIR 131072
#define SPLITK 4

typedef __attribute__((ext_vector_type(8))) short short8;
typedef __attribute__((ext_vector_type(4))) float f32x4;
typedef __attribute__((ext_vector_type(4))) unsigned short u16x4;
typedef __attribute__((ext_vector_type(8))) unsigned short u16x8;

__device__ inline unsigned short f2bf(float f) {
  union { float f; unsigned u; } v; v.f = f;
  unsigned r = v.u + 0x7fffu + ((v.u >> 16) & 1u);
  return (unsigned short)(r >> 16);
}
__device__ inline float bf2f(unsigned short b) {
  union { unsigned u; float f; } v; v.u = ((unsigned)b) << 16; return v.f;
}
__device__ inline void gload16(const void* g, void* l) {
  __builtin_amdgcn_global_load_lds((const __attribute__((address_space(1))) unsigned int*)g,
                                   (__attribute__((address_space(3))) unsigned int*)l, 16, 0, 0);
}

// ---------------- both weight casts in one launch (y=0 -> w_q, y=1 -> w_k) ----------------
__global__ __launch_bounds__(256) void k_castw(const float* __restrict__ wq,
                                               const float* __restrict__ wk,
                                               unsigned short* __restrict__ dst) {
  const float* src = blockIdx.y ? wk : wq;
  unsigned short* d = dst + (size_t)blockIdx.y * D_FEAT * D_FEAT;
  int i = (blockIdx.x * 256 + threadIdx.x) * 4;
  float4 v = *(const float4*)&src[i];
  ushort4 o;
  o.x = f2bf(v.x); o.y = f2bf(v.y); o.z = f2bf(v.z); o.w = f2bf(v.w);
  *(ushort4*)&d[i] = o;
}

// ---------------- x (4096x512 f32) -> xb bf16 AND xT bf16 (512x4096), one read ----------------
__global__ __launch_bounds__(256) void k_xprep(const float* __restrict__ x,
                                               unsigned short* __restrict__ xb,
                                               unsigned short* __restrict__ xT) {
  __shared__ float t[32][33];
  int bx = blockIdx.x, by = blockIdx.y;
  int tx = threadIdx.x & 31, ty = threadIdx.x >> 5;
  #pragma unroll
  for (int r = 0; r < 4; ++r) {
    int row = by * 32 + ty + r * 8;
    float v = x[(size_t)row * D_FEAT + bx * 32 + tx];
    t[ty + r * 8][tx] = v;
    xb[(size_t)row * D_FEAT + bx * 32 + tx] = f2bf(v);
  }
  __syncthreads();
  #pragma unroll
  for (int r = 0; r < 4; ++r)
    xT[(size_t)(bx * 32 + ty + r * 8) * N_INST + by * 32 + tx] = f2bf(t[tx][ty + r * 8]);
}

// ---------------- 2 rows/block: bf16 mask (diag=1) + off-diag count + nibble validity ----------------
__global__ __launch_bounds__(256) void k_mask_acnt(const float* __restrict__ agg,
                                                   unsigned short* __restrict__ maskb,
                                                   int* __restrict__ acnt,
                                                   unsigned char* __restrict__ vbits) {
  int i0 = blockIdx.x * 2;
  const f32x4* r0 = (const f32x4*)(agg + (size_t)i0 * N_INST);
  const f32x4* r1 = (const f32x4*)(agg + (size_t)(i0 + 1) * N_INST);
  u16x4* m0 = (u16x4*)(maskb + (size_t)i0 * N_INST);
  u16x4* m1 = (u16x4*)(maskb + (size_t)(i0 + 1) * N_INST);
  unsigned char* v0r = vbits + (size_t)i0 * (N_INST / 4);
  unsigned char* v1r = vbits + (size_t)(i0 + 1) * (N_INST / 4);
  int tid = threadIdx.x;
  f32x4 v[8];
  #pragma unroll
  for (int u = 0; u < 4; ++u) {
    v[u]     = __builtin_nontemporal_load(&r0[u * 256 + tid]);
    v[4 + u] = __builtin_nontemporal_load(&r1[u * 256 + tid]);
  }
  int cnt0 = 0, cnt1 = 0;
  #pragma unroll
  for (int u = 0; u < 4; ++u) {
    int t = u * 256 + tid;
    int j = t * 4;
    {
      f32x4 w = v[u];
      int b0 = (w[0] != 0.f), b1 = (w[1] != 0.f), b2 = (w[2] != 0.f), b3 = (w[3] != 0.f);
      u16x4 m;
      m[0] = b0 ? 0x3F80 : 0; m[1] = b1 ? 0x3F80 : 0;
      m[2] = b2 ? 0x3F80 : 0; m[3] = b3 ? 0x3F80 : 0;
      cnt0 += b0 + b1 + b2 + b3;
      v0r[t] = (unsigned char)(b0 | (b1 << 1) | (b2 << 2) | (b3 << 3));
      if (i0 >= j && i0 < j + 4) {
        int d = i0 - j;
        m[d] = 0x3F80;
        cnt0 -= (w[d] != 0.f);
      }
      __builtin_nontemporal_store(m, &m0[t]);
    }
    {
      f32x4 w = v[4 + u];
      int i1 = i0 + 1;
      int b0 = (w[0] != 0.f), b1 = (w[1] != 0.f), b2 = (w[2] != 0.f), b3 = (w[3] != 0.f);
      u16x4 m;
      m[0] = b0 ? 0x3F80 : 0; m[1] = b1 ? 0x3F80 : 0;
      m[2] = b2 ? 0x3F80 : 0; m[3] = b3 ? 0x3F80 : 0;
      cnt1 += b0 + b1 + b2 + b3;
      v1r[t] = (unsigned char)(b0 | (b1 << 1) | (b2 << 2) | (b3 << 3));
      if (i1 >= j && i1 < j + 4) {
        int d = i1 - j;
        m[d] = 0x3F80;
        cnt1 -= (w[d] != 0.f);
      }
      __builtin_nontemporal_store(m, &m1[t]);
    }
  }
  #pragma unroll
  for (int msk = 1; msk < 64; msk <<= 1) {
    cnt0 += __shfl_xor(cnt0, msk);
    cnt1 += __shfl_xor(cnt1, msk);
  }
  __shared__ int wsum[4][2];
  if ((threadIdx.x & 63) == 0) {
    wsum[threadIdx.x >> 6][0] = cnt0;
    wsum[threadIdx.x >> 6][1] = cnt1;
  }
  __syncthreads();
  if (threadIdx.x == 0)
    acnt[i0] = wsum[0][0] + wsum[1][0] + wsum[2][0] + wsum[3][0];
  if (threadIdx.x == 1)
    acnt[i0 + 1] = wsum[0][1] + wsum[1][1] + wsum[2][1] + wsum[3][1];
}

// ---------------- NT bf16 MFMA GEMM, BM=128, BN templated, BK=64, dbuf (R15 proven) ----------------
// R16 post-mortem: single-buffer NB=1 regressed (+6us) — the per-K-step barrier
// drain costs more than 2->4 blocks/CU recovers. Dbuf + gload_lds stays.
template<int BIAS, int CBF16, int BN>
__global__ __launch_bounds__(256, 2) void k_gemm(const unsigned short* __restrict__ A,
                                                 const unsigned short* __restrict__ B,
                                                 const float* __restrict__ bias0,
                                                 const float* __restrict__ bias1,
                                                 void* __restrict__ Cv,
                                                 int M, int N, int K, int klen) {
  constexpr int NI = BN / 32;
  constexpr int BCH = BN / 32;
  __shared__ __align__(16) unsigned short lA[2][128 * 64];
  __shared__ __align__(16) unsigned short lB[2][BN * 64];
  int tid = threadIdx.x, wave = tid >> 6, lane = tid & 63;
  int wm = wave & 1, wn = wave >> 1;
  int gx = gridDim.x;
  int nxy = gx * gridDim.y;
  int lin = blockIdx.x + gx * blockIdx.y;
  int nch = nxy >> 3;
  int nl = (lin & 7) * nch + (lin >> 3);
  int bx = nl % gx, by = nl / gx;
  int bm = by * 128, bn = bx * BN;
  int kbase = blockIdx.z * klen;
  int srow = lane >> 3;
  int sg = (lane & 7) ^ srow;
  const unsigned short* ag[4];
  const unsigned short* bg[BCH];
  #pragma unroll
  for (int p = 0; p < 4; ++p) {
    int row = (wave * 4 + p) * 8 + srow;
    ag[p] = A + (size_t)(bm + row) * K + kbase + sg * 8;
  }
  #pragma unroll
  for (int p = 0; p < BCH; ++p) {
    int row = (wave * BCH + p) * 8 + srow;
    bg[p] = B + (size_t)(bn + row) * K + kbase + sg * 8;
  }
  auto stage = [&](int buf) {
    #pragma unroll
    for (int p = 0; p < 4; ++p) { gload16(ag[p], &lA[buf][(wave * 4 + p) * 512]); ag[p] += 64; }
    #pragma unroll
    for (int p = 0; p < BCH; ++p) { gload16(bg[p], &lB[buf][(wave * BCH + p) * 512]); bg[p] += 64; }
  };
  f32x4 acc[4][NI] = {};
  int nt = klen / 64;
  stage(0);
  __syncthreads();
  int cur = 0;
  int lrow = lane & 15, glq = lane >> 4;
  for (int t = 0; t < nt; ++t) {
    if (t + 1 < nt) stage(cur ^ 1);
    short8 bf[2][NI];
    #pragma unroll
    for (int kk = 0; kk < 2; ++kk)
      #pragma unroll
      for (int ni = 0; ni < NI; ++ni) {
        int row = wn * (BN / 2) + ni * 16 + lrow;
        int pg = (kk * 4 + glq) ^ (row & 7);
        bf[kk][ni] = *(const short8*)&lB[cur][row * 64 + pg * 8];
      }
    #pragma unroll
    for (int mi = 0; mi < 4; ++mi)
      #pragma unroll
      for (int kk = 0; kk < 2; ++kk) {
        int row = wm * 64 + mi * 16 + lrow;
        int pg = (kk * 4 + glq) ^ (row & 7);
        short8 af = *(const short8*)&lA[cur][row * 64 + pg * 8];
        #pragma unroll
        for (int ni = 0; ni < NI; ++ni)
          acc[mi][ni] = __builtin_amdgcn_mfma_f32_16x16x32_bf16(af, bf[kk][ni], acc[mi][ni], 0, 0, 0);
      }
    __syncthreads();
    cur ^= 1;
  }
  #pragma unroll
  for (int mi = 0; mi < 4; ++mi)
    #pragma unroll
    for (int ni = 0; ni < NI; ++ni) {
      int col = bn + wn * (BN / 2) + ni * 16 + lrow;
      float bv = 0.f;
      if (BIAS) bv = (col < 512) ? bias0[col] : bias1[col - 512];
      #pragma unroll
      for (int j = 0; j < 4; ++j) {
        int row = bm + wm * 64 + mi * 16 + glq * 4 + j;
        float vv = acc[mi][ni][j] + bv;
        if (CBF16) {
          unsigned short* C = (unsigned short*)Cv + (size_t)blockIdx.z * M * N;
          C[(size_t)row * N + col] = f2bf(vv);
        } else {
          float* C = (float*)Cv + (size_t)blockIdx.z * M * N;
          C[(size_t)row * N + col] = vv;
        }
      }
    }
}

// ---------------- per-pair exp(score): 16 lanes/pair (4 pairs/wave), 8 loads in flight ----------------
__global__ __launch_bounds__(256) void k_scores(const unsigned short* __restrict__ QKb,
                                                const int* __restrict__ pairs,
                                                const unsigned char* __restrict__ vbits,
                                                float* __restrict__ es,
                                                float* __restrict__ sumexp,
                                                int* __restrict__ scnt) {
  int wave = threadIdx.x >> 6, lane = threadIdx.x & 63;
  int q = lane >> 4, ql = lane & 15;
  int e = (blockIdx.x * 4 + wave) * 4 + q;
  int2 pr = *(const int2*)&pairs[2 * e];
  int sub = pr.x, obj = pr.y;
  unsigned char nb = vbits[(size_t)sub * (N_INST / 4) + (obj >> 2)];
  bool valid = (sub != obj) && ((nb >> (obj & 3)) & 1);
  if (!valid && ql == 0) es[(size_t)e * 8] = -1.f;
  if (__ballot(valid) == 0ull) return;   // all 4 pairs invalid -> retire wave
  float p[4] = {0.f, 0.f, 0.f, 0.f};
  if (valid) {
    short8 qv[4], kv[4];
    #pragma unroll
    for (int c = 0; c < 4; ++c) {
      qv[c] = *(const short8*)&QKb[(size_t)sub * 1024 + c * 128 + ql * 8];
      kv[c] = *(const short8*)&QKb[(size_t)obj * 1024 + 512 + c * 128 + ql * 8];
    }
    #pragma unroll
    for (int c = 0; c < 4; ++c)
      #pragma unroll
      for (int j = 0; j < 8; ++j)
        p[c] += bf2f((unsigned short)qv[c][j]) * bf2f((unsigned short)kv[c][j]);
  }
  #pragma unroll
  for (int c = 0; c < 4; ++c) {
    p[c] += __shfl_xor(p[c], 1);
    p[c] += __shfl_xor(p[c], 2);
    p[c] += __shfl_xor(p[c], 4);
  }
  if (valid && (ql & 7) == 0) {
    int hi = ql >> 3;                   // 0 or 1
    #pragma unroll
    for (int c = 0; c < 4; ++c) {
      int h = 2 * c + hi;
      float ev = expf(p[c] * 0.125f);   // / sqrt(64)
      es[(size_t)e * 8 + h] = ev;
      atomicAdd(&sumexp[sub * 8 + h], ev);
    }
    if (ql == 0) atomicAdd(&scnt[sub], 1);
  }
}

// ---------------- per-row denominators -> invden, base ----------------
__global__ __launch_bounds__(256) void k_denom(const float* __restrict__ sumexp,
                                               const int* __restrict__ scnt,
                                               const int* __restrict__ acnt,
                                               float* __restrict__ invden,
                                               float* __restrict__ base) {
  int i = blockIdx.x * 256 + threadIdx.x;
  if (i >= N_INST) return;
  float c0 = (float)(acnt[i] - scnt[i]);
  const float E0 = expf(1e-7f);
  float bsum = 0.f;
  #pragma unroll
  for (int h = 0; h < NHEAD; ++h) {
    float inv = 1.0f / (E0 + c0 + sumexp[i * NHEAD + h]);
    invden[i * NHEAD + h] = inv;
    bsum += inv;
  }
  base[i] = bsum * (1.0f / NHEAD);
}

// ---------------- scatter ratio entries into mask ----------------
__global__ __launch_bounds__(256) void k_scatter(const int* __restrict__ pairs,
                                                 const float* __restrict__ es,
                                                 const float* __restrict__ invden,
                                                 const float* __restrict__ base,
                                                 unsigned short* __restrict__ maskb) {
  int e = blockIdx.x * 256 + threadIdx.x;
  if (e >= NPAIR) return;
  float4 e0 = *(const float4*)&es[(size_t)e * 8];
  if (e0.x < 0.f) return;
  float4 e1 = *(const float4*)&es[(size_t)e * 8 + 4];
  int sub = pairs[2 * e], obj = pairs[2 * e + 1];
  const float* inv = &invden[sub * 8];
  float f = e0.x * inv[0] + e0.y * inv[1] + e0.z * inv[2] + e0.w * inv[3] +
            e1.x * inv[4] + e1.y * inv[5] + e1.z * inv[6] + e1.w * inv[7];
  maskb[(size_t)sub * N_INST + obj] = f2bf(f * 0.125f / base[sub]);
}

// ---------------- reduce split-K=4 bf16 partials + row scale (16B loads) ----------------
__global__ __launch_bounds__(256) void k_redscale(const unsigned short* __restrict__ P,
                                                  const float* __restrict__ base,
                                                  float* __restrict__ out) {
  size_t idx = ((size_t)blockIdx.x * 256 + threadIdx.x) * 8;
  int i = (int)(idx >> 9);
  const size_t S = (size_t)N_INST * 512;
  u16x8 v[SPLITK];
  #pragma unroll
  for (int z = 0; z < SPLITK; ++z)
    v[z] = *(const u16x8*)&P[idx + z * S];
  float s = base[i];
  float4 o0, o1;
  #pragma unroll
  for (int j = 0; j < 4; ++j) {
    float a = 0.f, b = 0.f;
    #pragma unroll
    for (int z = 0; z < SPLITK; ++z) {
      a += bf2f(v[z][j]);
      b += bf2f(v[z][4 + j]);
    }
    ((float*)&o0)[j] = s * a;
    ((float*)&o1)[j] = s * b;
  }
  *(float4*)&out[idx] = o0;
  *(float4*)&out[idx + 4] = o1;
}

extern "C" void kernel_launch(void* const* d_in, const int* in_sizes, int n_in,
                              void* d_out, int out_size, void* d_ws, size_t ws_size,
                              hipStream_t stream) {
  const float* x   = (const float*)d_in[0];
  const float* agg = (const float*)d_in[1];
  const int*   prs = (const int*)d_in[2];
  const float* w_q = (const float*)d_in[3];
  const float* b_q = (const float*)d_in[4];
  const float* w_k = (const float*)d_in[5];
  const float* b_k = (const float*)d_in[6];
  float* out = (float*)d_out;

  char* ws = (char*)d_ws;
  size_t off = 0;
  auto alloc = [&](size_t bytes) -> void* {
    void* p = ws + off;
    off += (bytes + 255) & ~(size_t)255;
    return p;
  };
  unsigned short* xb    = (unsigned short*)alloc((size_t)N_INST * D_FEAT * 2);
  unsigned short* xbT   = (unsigned short*)alloc((size_t)D_FEAT * N_INST * 2);
  unsigned short* wqkb  = (unsigned short*)alloc((size_t)1024 * D_FEAT * 2);
  void*           QKP   = alloc((size_t)N_INST * 512 * 2 * SPLITK);  // 8MB QK table; reused as 4x bf16 partials (16MB)
  float*          es    = (float*)alloc((size_t)NPAIR * NHEAD * 4);
  float*          sumexp= (float*)alloc((size_t)N_INST * NHEAD * 4);
  int*            scnt  = (int*)alloc((size_t)N_INST * 4);
  int*            acnt  = (int*)alloc((size_t)N_INST * 4);
  float*          invden= (float*)alloc((size_t)N_INST * NHEAD * 4);
  float*          base  = (float*)alloc((size_t)N_INST * 4);
  unsigned char*  vbits = (unsigned char*)alloc((size_t)N_INST * (N_INST / 4));
  unsigned short* maskb = (unsigned short*)alloc((size_t)N_INST * N_INST * 2);

  // sumexp (128KB, 256-aligned) and scnt (16KB) are adjacent -> one memset
  hipMemsetAsync(sumexp, 0, (size_t)N_INST * NHEAD * 4 + (size_t)N_INST * 4, stream);

  k_castw<<<dim3(D_FEAT * D_FEAT / 4 / 256, 2), 256, 0, stream>>>(w_q, w_k, wqkb);
  k_xprep<<<dim3(D_FEAT / 32, N_INST / 32), 256, 0, stream>>>(x, xb, xbT);
  k_mask_acnt<<<dim3(N_INST / 2), 256, 0, stream>>>(agg, maskb, acnt, vbits);

  // fused Q|K projection (dbuf): C (4096x1024 bf16) = xb * wqkb^T + bias
  k_gemm<1, 1, 64><<<dim3(1024 / 64, N_INST / 128, 1), 256, 0, stream>>>(
      xb, wqkb, b_q, b_k, QKP, N_INST, 1024, D_FEAT, D_FEAT);

  k_scores<<<dim3(NPAIR / 16), 256, 0, stream>>>((const unsigned short*)QKP, prs, vbits, es, sumexp, scnt);
  k_denom<<<dim3(N_INST / 256), 256, 0, stream>>>(sumexp, scnt, acnt, invden, base);
  k_scatter<<<dim3(NPAIR / 256), 256, 0, stream>>>(prs, es, invden, base, maskb);

  // bf16 partials = maskb (4096x4096) * xbT (512x4096)^T, 128x128 tile, dbuf, split-K=4
  k_gemm<0, 1, 128><<<dim3(512 / 128, N_INST / 128, SPLITK), 256, 0, stream>>>(
      maskb, xbT, nullptr, nullptr, QKP, N_INST, 512, N_INST, N_INST / SPLITK);

  k_redscale<<<dim3(N_INST * 512 / 8 / 256), 256, 0, stream>>>((const unsigned short*)QKP, base, out);
}

// Round 18
// 106.214 us; speedup vs baseline: 1.0701x; 1.0256x over previous
//
#include <hip/hip_runtime.h>

#define N_INST 4096
#define D_FEAT 512
#define NHEAD 8
#define NPAIR 131072
#define SPLITK 4

typedef __attribute__((ext_vector_type(8))) short short8;
typedef __attribute__((ext_vector_type(4))) float f32x4;
typedef __attribute__((ext_vector_type(4))) unsigned short u16x4;
typedef __attribute__((ext_vector_type(8))) unsigned short u16x8;

__device__ inline unsigned short f2bf(float f) {
  union { float f; unsigned u; } v; v.f = f;
  unsigned r = v.u + 0x7fffu + ((v.u >> 16) & 1u);
  return (unsigned short)(r >> 16);
}
__device__ inline float bf2f(unsigned short b) {
  union { unsigned u; float f; } v; v.u = ((unsigned)b) << 16; return v.f;
}
__device__ inline void gload16(const void* g, void* l) {
  __builtin_amdgcn_global_load_lds((const __attribute__((address_space(1))) unsigned int*)g,
                                   (__attribute__((address_space(3))) unsigned int*)l, 16, 0, 0);
}

// ---------------- both weight casts in one launch (y=0 -> w_q, y=1 -> w_k) ----------------
__global__ __launch_bounds__(256) void k_castw(const float* __restrict__ wq,
                                               const float* __restrict__ wk,
                                               unsigned short* __restrict__ dst) {
  const float* src = blockIdx.y ? wk : wq;
  unsigned short* d = dst + (size_t)blockIdx.y * D_FEAT * D_FEAT;
  int i = (blockIdx.x * 256 + threadIdx.x) * 4;
  float4 v = *(const float4*)&src[i];
  ushort4 o;
  o.x = f2bf(v.x); o.y = f2bf(v.y); o.z = f2bf(v.z); o.w = f2bf(v.w);
  *(ushort4*)&d[i] = o;
}

// ---------------- x (4096x512 f32) -> xb bf16 AND xT bf16 (512x4096), one read ----------------
__global__ __launch_bounds__(256) void k_xprep(const float* __restrict__ x,
                                               unsigned short* __restrict__ xb,
                                               unsigned short* __restrict__ xT) {
  __shared__ float t[32][33];
  int bx = blockIdx.x, by = blockIdx.y;
  int tx = threadIdx.x & 31, ty = threadIdx.x >> 5;
  #pragma unroll
  for (int r = 0; r < 4; ++r) {
    int row = by * 32 + ty + r * 8;
    float v = x[(size_t)row * D_FEAT + bx * 32 + tx];
    t[ty + r * 8][tx] = v;
    xb[(size_t)row * D_FEAT + bx * 32 + tx] = f2bf(v);
  }
  __syncthreads();
  #pragma unroll
  for (int r = 0; r < 4; ++r)
    xT[(size_t)(bx * 32 + ty + r * 8) * N_INST + by * 32 + tx] = f2bf(t[tx][ty + r * 8]);
}

// ---------------- 2 rows/block: bf16 mask (diag=1) + off-diag count + nibble validity ----------------
__global__ __launch_bounds__(256) void k_mask_acnt(const float* __restrict__ agg,
                                                   unsigned short* __restrict__ maskb,
                                                   int* __restrict__ acnt,
                                                   unsigned char* __restrict__ vbits) {
  int i0 = blockIdx.x * 2;
  const f32x4* r0 = (const f32x4*)(agg + (size_t)i0 * N_INST);
  const f32x4* r1 = (const f32x4*)(agg + (size_t)(i0 + 1) * N_INST);
  u16x4* m0 = (u16x4*)(maskb + (size_t)i0 * N_INST);
  u16x4* m1 = (u16x4*)(maskb + (size_t)(i0 + 1) * N_INST);
  unsigned char* v0r = vbits + (size_t)i0 * (N_INST / 4);
  unsigned char* v1r = vbits + (size_t)(i0 + 1) * (N_INST / 4);
  int tid = threadIdx.x;
  f32x4 v[8];
  #pragma unroll
  for (int u = 0; u < 4; ++u) {
    v[u]     = __builtin_nontemporal_load(&r0[u * 256 + tid]);
    v[4 + u] = __builtin_nontemporal_load(&r1[u * 256 + tid]);
  }
  int cnt0 = 0, cnt1 = 0;
  #pragma unroll
  for (int u = 0; u < 4; ++u) {
    int t = u * 256 + tid;
    int j = t * 4;
    {
      f32x4 w = v[u];
      int b0 = (w[0] != 0.f), b1 = (w[1] != 0.f), b2 = (w[2] != 0.f), b3 = (w[3] != 0.f);
      u16x4 m;
      m[0] = b0 ? 0x3F80 : 0; m[1] = b1 ? 0x3F80 : 0;
      m[2] = b2 ? 0x3F80 : 0; m[3] = b3 ? 0x3F80 : 0;
      cnt0 += b0 + b1 + b2 + b3;
      v0r[t] = (unsigned char)(b0 | (b1 << 1) | (b2 << 2) | (b3 << 3));
      if (i0 >= j && i0 < j + 4) {
        int d = i0 - j;
        m[d] = 0x3F80;
        cnt0 -= (w[d] != 0.f);
      }
      __builtin_nontemporal_store(m, &m0[t]);
    }
    {
      f32x4 w = v[4 + u];
      int i1 = i0 + 1;
      int b0 = (w[0] != 0.f), b1 = (w[1] != 0.f), b2 = (w[2] != 0.f), b3 = (w[3] != 0.f);
      u16x4 m;
      m[0] = b0 ? 0x3F80 : 0; m[1] = b1 ? 0x3F80 : 0;
      m[2] = b2 ? 0x3F80 : 0; m[3] = b3 ? 0x3F80 : 0;
      cnt1 += b0 + b1 + b2 + b3;
      v1r[t] = (unsigned char)(b0 | (b1 << 1) | (b2 << 2) | (b3 << 3));
      if (i1 >= j && i1 < j + 4) {
        int d = i1 - j;
        m[d] = 0x3F80;
        cnt1 -= (w[d] != 0.f);
      }
      __builtin_nontemporal_store(m, &m1[t]);
    }
  }
  #pragma unroll
  for (int msk = 1; msk < 64; msk <<= 1) {
    cnt0 += __shfl_xor(cnt0, msk);
    cnt1 += __shfl_xor(cnt1, msk);
  }
  __shared__ int wsum[4][2];
  if ((threadIdx.x & 63) == 0) {
    wsum[threadIdx.x >> 6][0] = cnt0;
    wsum[threadIdx.x >> 6][1] = cnt1;
  }
  __syncthreads();
  if (threadIdx.x == 0)
    acnt[i0] = wsum[0][0] + wsum[1][0] + wsum[2][0] + wsum[3][0];
  if (threadIdx.x == 1)
    acnt[i0 + 1] = wsum[0][1] + wsum[1][1] + wsum[2][1] + wsum[3][1];
}

// ---------------- NT bf16 MFMA GEMM, BM=128, BN templated, BK=64, dbuf (proven) ----------------
template<int BIAS, int CBF16, int BN>
__global__ __launch_bounds__(256, 2) void k_gemm(const unsigned short* __restrict__ A,
                                                 const unsigned short* __restrict__ B,
                                                 const float* __restrict__ bias0,
                                                 const float* __restrict__ bias1,
                                                 void* __restrict__ Cv,
                                                 int M, int N, int K, int klen) {
  constexpr int NI = BN / 32;
  constexpr int BCH = BN / 32;
  __shared__ __align__(16) unsigned short lA[2][128 * 64];
  __shared__ __align__(16) unsigned short lB[2][BN * 64];
  int tid = threadIdx.x, wave = tid >> 6, lane = tid & 63;
  int wm = wave & 1, wn = wave >> 1;
  int gx = gridDim.x;
  int nxy = gx * gridDim.y;
  int lin = blockIdx.x + gx * blockIdx.y;
  int nch = nxy >> 3;
  int nl = (lin & 7) * nch + (lin >> 3);
  int bx = nl % gx, by = nl / gx;
  int bm = by * 128, bn = bx * BN;
  int kbase = blockIdx.z * klen;
  int srow = lane >> 3;
  int sg = (lane & 7) ^ srow;
  const unsigned short* ag[4];
  const unsigned short* bg[BCH];
  #pragma unroll
  for (int p = 0; p < 4; ++p) {
    int row = (wave * 4 + p) * 8 + srow;
    ag[p] = A + (size_t)(bm + row) * K + kbase + sg * 8;
  }
  #pragma unroll
  for (int p = 0; p < BCH; ++p) {
    int row = (wave * BCH + p) * 8 + srow;
    bg[p] = B + (size_t)(bn + row) * K + kbase + sg * 8;
  }
  auto stage = [&](int buf) {
    #pragma unroll
    for (int p = 0; p < 4; ++p) { gload16(ag[p], &lA[buf][(wave * 4 + p) * 512]); ag[p] += 64; }
    #pragma unroll
    for (int p = 0; p < BCH; ++p) { gload16(bg[p], &lB[buf][(wave * BCH + p) * 512]); bg[p] += 64; }
  };
  f32x4 acc[4][NI] = {};
  int nt = klen / 64;
  stage(0);
  __syncthreads();
  int cur = 0;
  int lrow = lane & 15, glq = lane >> 4;
  for (int t = 0; t < nt; ++t) {
    if (t + 1 < nt) stage(cur ^ 1);
    short8 bf[2][NI];
    #pragma unroll
    for (int kk = 0; kk < 2; ++kk)
      #pragma unroll
      for (int ni = 0; ni < NI; ++ni) {
        int row = wn * (BN / 2) + ni * 16 + lrow;
        int pg = (kk * 4 + glq) ^ (row & 7);
        bf[kk][ni] = *(const short8*)&lB[cur][row * 64 + pg * 8];
      }
    #pragma unroll
    for (int mi = 0; mi < 4; ++mi)
      #pragma unroll
      for (int kk = 0; kk < 2; ++kk) {
        int row = wm * 64 + mi * 16 + lrow;
        int pg = (kk * 4 + glq) ^ (row & 7);
        short8 af = *(const short8*)&lA[cur][row * 64 + pg * 8];
        #pragma unroll
        for (int ni = 0; ni < NI; ++ni)
          acc[mi][ni] = __builtin_amdgcn_mfma_f32_16x16x32_bf16(af, bf[kk][ni], acc[mi][ni], 0, 0, 0);
      }
    __syncthreads();
    cur ^= 1;
  }
  #pragma unroll
  for (int mi = 0; mi < 4; ++mi)
    #pragma unroll
    for (int ni = 0; ni < NI; ++ni) {
      int col = bn + wn * (BN / 2) + ni * 16 + lrow;
      float bv = 0.f;
      if (BIAS) bv = (col < 512) ? bias0[col] : bias1[col - 512];
      #pragma unroll
      for (int j = 0; j < 4; ++j) {
        int row = bm + wm * 64 + mi * 16 + glq * 4 + j;
        float vv = acc[mi][ni][j] + bv;
        if (CBF16) {
          unsigned short* C = (unsigned short*)Cv + (size_t)blockIdx.z * M * N;
          C[(size_t)row * N + col] = f2bf(vv);
        } else {
          float* C = (float*)Cv + (size_t)blockIdx.z * M * N;
          C[(size_t)row * N + col] = vv;
        }
      }
    }
}

// ---------------- per-pair exp(score): 32-lane half per pair (2 pairs/wave) — R15 proven ----------------
// MLP-vs-TLP sweet spot: 4 outstanding 16B gathers/lane, 16384 blocks.
// R17 post-mortem: 4 pairs/wave (8192 blocks) lost ~2us — TLP cut too deep.
__global__ __launch_bounds__(256) void k_scores(const unsigned short* __restrict__ QKb,
                                                const int* __restrict__ pairs,
                                                const unsigned char* __restrict__ vbits,
                                                float* __restrict__ es,
                                                float* __restrict__ sumexp,
                                                int* __restrict__ scnt) {
  int wave = threadIdx.x >> 6, lane = threadIdx.x & 63;
  int half = lane >> 5, hl = lane & 31;
  int e = (blockIdx.x * 4 + wave) * 2 + half;
  int2 pr = *(const int2*)&pairs[2 * e];
  int sub = pr.x, obj = pr.y;
  unsigned char nb = vbits[(size_t)sub * (N_INST / 4) + (obj >> 2)];
  bool valid = (sub != obj) && ((nb >> (obj & 3)) & 1);
  if (!valid && hl == 0) es[(size_t)e * 8] = -1.f;
  if (__ballot(valid) == 0ull) return;   // both halves invalid -> retire wave
  float pa = 0.f, pb = 0.f;
  if (valid) {
    short8 qa = *(const short8*)&QKb[(size_t)sub * 1024 + hl * 8];
    short8 qb = *(const short8*)&QKb[(size_t)sub * 1024 + 256 + hl * 8];
    short8 ka = *(const short8*)&QKb[(size_t)obj * 1024 + 512 + hl * 8];
    short8 kb = *(const short8*)&QKb[(size_t)obj * 1024 + 768 + hl * 8];
    #pragma unroll
    for (int j = 0; j < 8; ++j) {
      pa += bf2f((unsigned short)qa[j]) * bf2f((unsigned short)ka[j]);
      pb += bf2f((unsigned short)qb[j]) * bf2f((unsigned short)kb[j]);
    }
  }
  pa += __shfl_xor(pa, 1); pa += __shfl_xor(pa, 2); pa += __shfl_xor(pa, 4);
  pb += __shfl_xor(pb, 1); pb += __shfl_xor(pb, 2); pb += __shfl_xor(pb, 4);
  if (valid && (hl & 7) == 0) {
    int g = hl >> 3;                     // head group 0..3
    float ea = expf(pa * 0.125f);        // heads 0-3
    float eb = expf(pb * 0.125f);        // heads 4-7
    es[(size_t)e * 8 + g] = ea;
    es[(size_t)e * 8 + 4 + g] = eb;
    atomicAdd(&sumexp[sub * 8 + g], ea);
    atomicAdd(&sumexp[sub * 8 + 4 + g], eb);
    if (g == 0) atomicAdd(&scnt[sub], 1);
  }
}

// ---------------- per-row denominators -> invden, base ----------------
__global__ __launch_bounds__(256) void k_denom(const float* __restrict__ sumexp,
                                               const int* __restrict__ scnt,
                                               const int* __restrict__ acnt,
                                               float* __restrict__ invden,
                                               float* __restrict__ base) {
  int i = blockIdx.x * 256 + threadIdx.x;
  if (i >= N_INST) return;
  float c0 = (float)(acnt[i] - scnt[i]);
  const float E0 = expf(1e-7f);
  float bsum = 0.f;
  #pragma unroll
  for (int h = 0; h < NHEAD; ++h) {
    float inv = 1.0f / (E0 + c0 + sumexp[i * NHEAD + h]);
    invden[i * NHEAD + h] = inv;
    bsum += inv;
  }
  base[i] = bsum * (1.0f / NHEAD);
}

// ---------------- scatter ratio entries into mask ----------------
__global__ __launch_bounds__(256) void k_scatter(const int* __restrict__ pairs,
                                                 const float* __restrict__ es,
                                                 const float* __restrict__ invden,
                                                 const float* __restrict__ base,
                                                 unsigned short* __restrict__ maskb) {
  int e = blockIdx.x * 256 + threadIdx.x;
  if (e >= NPAIR) return;
  float4 e0 = *(const float4*)&es[(size_t)e * 8];
  if (e0.x < 0.f) return;
  float4 e1 = *(const float4*)&es[(size_t)e * 8 + 4];
  int sub = pairs[2 * e], obj = pairs[2 * e + 1];
  const float* inv = &invden[sub * 8];
  float f = e0.x * inv[0] + e0.y * inv[1] + e0.z * inv[2] + e0.w * inv[3] +
            e1.x * inv[4] + e1.y * inv[5] + e1.z * inv[6] + e1.w * inv[7];
  maskb[(size_t)sub * N_INST + obj] = f2bf(f * 0.125f / base[sub]);
}

// ---------------- reduce split-K=4 bf16 partials + row scale (16B loads) ----------------
__global__ __launch_bounds__(256) void k_redscale(const unsigned short* __restrict__ P,
                                                  const float* __restrict__ base,
                                                  float* __restrict__ out) {
  size_t idx = ((size_t)blockIdx.x * 256 + threadIdx.x) * 8;
  int i = (int)(idx >> 9);
  const size_t S = (size_t)N_INST * 512;
  u16x8 v[SPLITK];
  #pragma unroll
  for (int z = 0; z < SPLITK; ++z)
    v[z] = *(const u16x8*)&P[idx + z * S];
  float s = base[i];
  float4 o0, o1;
  #pragma unroll
  for (int j = 0; j < 4; ++j) {
    float a = 0.f, b = 0.f;
    #pragma unroll
    for (int z = 0; z < SPLITK; ++z) {
      a += bf2f(v[z][j]);
      b += bf2f(v[z][4 + j]);
    }
    ((float*)&o0)[j] = s * a;
    ((float*)&o1)[j] = s * b;
  }
  *(float4*)&out[idx] = o0;
  *(float4*)&out[idx + 4] = o1;
}

extern "C" void kernel_launch(void* const* d_in, const int* in_sizes, int n_in,
                              void* d_out, int out_size, void* d_ws, size_t ws_size,
                              hipStream_t stream) {
  const float* x   = (const float*)d_in[0];
  const float* agg = (const float*)d_in[1];
  const int*   prs = (const int*)d_in[2];
  const float* w_q = (const float*)d_in[3];
  const float* b_q = (const float*)d_in[4];
  const float* w_k = (const float*)d_in[5];
  const float* b_k = (const float*)d_in[6];
  float* out = (float*)d_out;

  char* ws = (char*)d_ws;
  size_t off = 0;
  auto alloc = [&](size_t bytes) -> void* {
    void* p = ws + off;
    off += (bytes + 255) & ~(size_t)255;
    return p;
  };
  unsigned short* xb    = (unsigned short*)alloc((size_t)N_INST * D_FEAT * 2);
  unsigned short* xbT   = (unsigned short*)alloc((size_t)D_FEAT * N_INST * 2);
  unsigned short* wqkb  = (unsigned short*)alloc((size_t)1024 * D_FEAT * 2);
  void*           QKP   = alloc((size_t)N_INST * 512 * 2 * SPLITK);  // 8MB QK table; reused as 4x bf16 partials (16MB)
  float*          es    = (float*)alloc((size_t)NPAIR * NHEAD * 4);
  float*          sumexp= (float*)alloc((size_t)N_INST * NHEAD * 4);
  int*            scnt  = (int*)alloc((size_t)N_INST * 4);
  int*            acnt  = (int*)alloc((size_t)N_INST * 4);
  float*          invden= (float*)alloc((size_t)N_INST * NHEAD * 4);
  float*          base  = (float*)alloc((size_t)N_INST * 4);
  unsigned char*  vbits = (unsigned char*)alloc((size_t)N_INST * (N_INST / 4));
  unsigned short* maskb = (unsigned short*)alloc((size_t)N_INST * N_INST * 2);

  // sumexp (128KB, 256-aligned) and scnt (16KB) are adjacent -> one memset
  hipMemsetAsync(sumexp, 0, (size_t)N_INST * NHEAD * 4 + (size_t)N_INST * 4, stream);

  k_castw<<<dim3(D_FEAT * D_FEAT / 4 / 256, 2), 256, 0, stream>>>(w_q, w_k, wqkb);
  k_xprep<<<dim3(D_FEAT / 32, N_INST / 32), 256, 0, stream>>>(x, xb, xbT);
  k_mask_acnt<<<dim3(N_INST / 2), 256, 0, stream>>>(agg, maskb, acnt, vbits);

  // fused Q|K projection (dbuf): C (4096x1024 bf16) = xb * wqkb^T + bias
  k_gemm<1, 1, 64><<<dim3(1024 / 64, N_INST / 128, 1), 256, 0, stream>>>(
      xb, wqkb, b_q, b_k, QKP, N_INST, 1024, D_FEAT, D_FEAT);

  k_scores<<<dim3(NPAIR / 8), 256, 0, stream>>>((const unsigned short*)QKP, prs, vbits, es, sumexp, scnt);
  k_denom<<<dim3(N_INST / 256), 256, 0, stream>>>(sumexp, scnt, acnt, invden, base);
  k_scatter<<<dim3(NPAIR / 256), 256, 0, stream>>>(prs, es, invden, base, maskb);

  // bf16 partials = maskb (4096x4096) * xbT (512x4096)^T, 128x128 tile, dbuf, split-K=4
  k_gemm<0, 1, 128><<<dim3(512 / 128, N_INST / 128, SPLITK), 256, 0, stream>>>(
      maskb, xbT, nullptr, nullptr, QKP, N_INST, 512, N_INST, N_INST / SPLITK);

  k_redscale<<<dim3(N_INST * 512 / 8 / 256), 256, 0, stream>>>((const unsigned short*)QKP, base, out);
}